// Round 1
// baseline (3923.875 us; speedup 1.0000x reference)
//
#include <hip/hip_runtime.h>
#include <math.h>

#define BB 32
#define TT 832
#define DD 256
#define NLAYER 4
#define NH 4
#define HDIM 64
#define FF 1024
#define SS 3
#define LMM 36
#define BT (BB*TT)      // 26624
#define NQ 192          // q positions per batch (t%13 in {1,4,7})
#define NHID 64         // head positions per batch (t%13 == 12)

static __device__ __forceinline__ float gelu_tanh(float x) {
    float x3 = x*x*x;
    return 0.5f*x*(1.0f + tanhf(0.7978845608028654f*(x + 0.044715f*x3)));
}

// ---------------------------------------------------------------------------
// C[M,N] = act(A[M,K] @ W[K,N] + bias) (+ residual). ACT: 0 none, 1 gelu, 2 leaky
// 64x64 tile, BK=16, 256 threads, 4x4 per thread.
// ---------------------------------------------------------------------------
template<int ACT, bool RES>
__global__ __launch_bounds__(256) void gemm_f32(
    const float* __restrict__ A, const float* __restrict__ W,
    const float* __restrict__ bias, const float* __restrict__ Rsd,
    float* __restrict__ C, int M, int N, int K)
{
    __shared__ float As[16][68];   // [k][m], pad 68 keeps float4 alignment
    __shared__ float Ws[16][68];   // [k][n]
    const int bm = blockIdx.x * 64;
    const int bn = blockIdx.y * 64;
    const int t = threadIdx.x;
    const int tx = t & 15, ty = t >> 4;
    float c[4][4] = {};
    for (int k0 = 0; k0 < K; k0 += 16) {
        {
            int row = bm + (t >> 2);
            int kk = (t & 3) * 4;
            float4 a = make_float4(0.f, 0.f, 0.f, 0.f);
            if (row < M) a = *(const float4*)(A + (size_t)row * K + k0 + kk);
            int mm = t >> 2;
            As[kk+0][mm] = a.x; As[kk+1][mm] = a.y; As[kk+2][mm] = a.z; As[kk+3][mm] = a.w;
        }
        {
            int kr = t >> 4;
            int col = (t & 15) * 4;
            *(float4*)&Ws[kr][col] = *(const float4*)(W + (size_t)(k0 + kr) * N + bn + col);
        }
        __syncthreads();
        #pragma unroll
        for (int kk = 0; kk < 16; ++kk) {
            float4 a4 = *(const float4*)&As[kk][ty*4];
            float4 b4 = *(const float4*)&Ws[kk][tx*4];
            float av[4] = {a4.x, a4.y, a4.z, a4.w};
            float bv[4] = {b4.x, b4.y, b4.z, b4.w};
            #pragma unroll
            for (int i = 0; i < 4; ++i)
                #pragma unroll
                for (int j = 0; j < 4; ++j)
                    c[i][j] = fmaf(av[i], bv[j], c[i][j]);
        }
        __syncthreads();
    }
    float4 b4 = *(const float4*)(bias + bn + tx*4);
    float bvals[4] = {b4.x, b4.y, b4.z, b4.w};
    #pragma unroll
    for (int i = 0; i < 4; ++i) {
        int row = bm + ty*4 + i;
        if (row >= M) continue;
        float tmp[4];
        #pragma unroll
        for (int j = 0; j < 4; ++j) {
            float v = c[i][j] + bvals[j];
            if (ACT == 1) v = gelu_tanh(v);
            if (ACT == 2) v = (v > 0.f) ? v : 0.01f * v;
            tmp[j] = v;
        }
        size_t off = (size_t)row * N + bn + tx*4;
        if (RES) {
            float4 r4 = *(const float4*)(Rsd + off);
            tmp[0] += r4.x; tmp[1] += r4.y; tmp[2] += r4.z; tmp[3] += r4.w;
        }
        *(float4*)(C + off) = make_float4(tmp[0], tmp[1], tmp[2], tmp[3]);
    }
}

// ---------------------------------------------------------------------------
// Flash-style causal attention. grid (T/64, H, B); Q/K stored transposed in LDS.
// ---------------------------------------------------------------------------
__global__ __launch_bounds__(256) void attn_causal(
    const float* __restrict__ Q, const float* __restrict__ K,
    const float* __restrict__ Vv, float* __restrict__ O)
{
    const int qt = blockIdx.x;
    const int h  = blockIdx.y;
    const int b  = blockIdx.z;
    __shared__ float Qst[64][68];  // [d][q]
    __shared__ float Kst[64][68];  // [d][k]
    __shared__ float Vs [64][68];  // [k][d]
    __shared__ float Ps [64][68];  // [q][k]
    const int t = threadIdx.x;
    const int tx = t & 15, ty = t >> 4;
    const size_t hb = ((size_t)b * TT) * DD + h * HDIM;

    {   // load Q tile transposed
        int row = t >> 2;
        int c0 = (t & 3) * 4;
        #pragma unroll
        for (int cc = 0; cc < 4; ++cc) {
            int col = cc*16 + c0;
            float4 qv = *(const float4*)(Q + hb + (size_t)(qt*64 + row) * DD + col);
            Qst[col+0][row] = qv.x; Qst[col+1][row] = qv.y;
            Qst[col+2][row] = qv.z; Qst[col+3][row] = qv.w;
        }
    }
    float m_i[4], l_i[4], acc[4][4];
    #pragma unroll
    for (int i = 0; i < 4; ++i) {
        m_i[i] = -1e30f; l_i[i] = 0.f;
        #pragma unroll
        for (int j = 0; j < 4; ++j) acc[i][j] = 0.f;
    }
    for (int kt = 0; kt <= qt; ++kt) {
        __syncthreads();  // protect prev-iter Ps/Vs reads and first-iter Qst
        {
            int row = t >> 2;
            int c0 = (t & 3) * 4;
            #pragma unroll
            for (int cc = 0; cc < 4; ++cc) {
                int col = cc*16 + c0;
                float4 kv = *(const float4*)(K + hb + (size_t)(kt*64 + row) * DD + col);
                Kst[col+0][row] = kv.x; Kst[col+1][row] = kv.y;
                Kst[col+2][row] = kv.z; Kst[col+3][row] = kv.w;
            }
            int vr = t >> 4;
            int vc = (t & 15) * 4;
            #pragma unroll
            for (int rr = 0; rr < 4; ++rr) {
                int row2 = rr*16 + vr;
                *(float4*)&Vs[row2][vc] =
                    *(const float4*)(Vv + hb + (size_t)(kt*64 + row2) * DD + vc);
            }
        }
        __syncthreads();
        float s[4][4] = {};
        #pragma unroll 8
        for (int d = 0; d < 64; ++d) {
            float4 q4 = *(const float4*)&Qst[d][ty*4];
            float4 k4 = *(const float4*)&Kst[d][tx*4];
            float qa[4] = {q4.x, q4.y, q4.z, q4.w};
            float kb[4] = {k4.x, k4.y, k4.z, k4.w};
            #pragma unroll
            for (int i = 0; i < 4; ++i)
                #pragma unroll
                for (int j = 0; j < 4; ++j)
                    s[i][j] = fmaf(qa[i], kb[j], s[i][j]);
        }
        #pragma unroll
        for (int i = 0; i < 4; ++i) {
            int tq = qt*64 + ty*4 + i;
            #pragma unroll
            for (int j = 0; j < 4; ++j) {
                int tk = kt*64 + tx*4 + j;
                float sv = s[i][j] * 0.125f;           // 1/sqrt(64)
                s[i][j] = (tk <= tq) ? sv : -1e9f;     // causal mask like ref
            }
        }
        #pragma unroll
        for (int i = 0; i < 4; ++i) {
            float rm = fmaxf(fmaxf(s[i][0], s[i][1]), fmaxf(s[i][2], s[i][3]));
            rm = fmaxf(rm, __shfl_xor(rm, 1));
            rm = fmaxf(rm, __shfl_xor(rm, 2));
            rm = fmaxf(rm, __shfl_xor(rm, 4));
            rm = fmaxf(rm, __shfl_xor(rm, 8));
            float mnew = fmaxf(m_i[i], rm);
            float alpha = expf(m_i[i] - mnew);
            m_i[i] = mnew;
            float rs = 0.f;
            #pragma unroll
            for (int j = 0; j < 4; ++j) {
                float p = expf(s[i][j] - mnew);
                s[i][j] = p;
                rs += p;
            }
            rs += __shfl_xor(rs, 1);
            rs += __shfl_xor(rs, 2);
            rs += __shfl_xor(rs, 4);
            rs += __shfl_xor(rs, 8);
            l_i[i] = l_i[i] * alpha + rs;
            #pragma unroll
            for (int j = 0; j < 4; ++j) acc[i][j] *= alpha;
        }
        #pragma unroll
        for (int i = 0; i < 4; ++i)
            *(float4*)&Ps[ty*4+i][tx*4] = make_float4(s[i][0], s[i][1], s[i][2], s[i][3]);
        __syncthreads();
        #pragma unroll 4
        for (int kk = 0; kk < 64; ++kk) {
            float4 v4 = *(const float4*)&Vs[kk][tx*4];
            float vb[4] = {v4.x, v4.y, v4.z, v4.w};
            float pa[4];
            #pragma unroll
            for (int i = 0; i < 4; ++i) pa[i] = Ps[ty*4+i][kk];
            #pragma unroll
            for (int i = 0; i < 4; ++i)
                #pragma unroll
                for (int j = 0; j < 4; ++j)
                    acc[i][j] = fmaf(pa[i], vb[j], acc[i][j]);
        }
    }
    #pragma unroll
    for (int i = 0; i < 4; ++i) {
        float inv = 1.f / l_i[i];
        *(float4*)(O + hb + (size_t)(qt*64 + ty*4 + i) * DD + tx*4) =
            make_float4(acc[i][0]*inv, acc[i][1]*inv, acc[i][2]*inv, acc[i][3]*inv);
    }
}

// ---------------------------------------------------------------------------
// LayerNorm, one row per wave (D=256 -> one float4 per lane)
// ---------------------------------------------------------------------------
__global__ __launch_bounds__(256) void ln_kernel(const float* __restrict__ Xin,
    const float* __restrict__ sc, const float* __restrict__ bi,
    float* __restrict__ Y, int M)
{
    int row = blockIdx.x * 4 + (threadIdx.x >> 6);
    if (row >= M) return;
    int lane = threadIdx.x & 63;
    float4 xv = *(const float4*)(Xin + (size_t)row * DD + lane*4);
    float sum = xv.x + xv.y + xv.z + xv.w;
    float sq  = xv.x*xv.x + xv.y*xv.y + xv.z*xv.z + xv.w*xv.w;
    #pragma unroll
    for (int m = 32; m; m >>= 1) { sum += __shfl_xor(sum, m); sq += __shfl_xor(sq, m); }
    float mean = sum * (1.f/256.f);
    float var  = sq * (1.f/256.f) - mean*mean;
    float rs = rsqrtf(var + 1e-5f);
    float4 sv = *(const float4*)(sc + lane*4);
    float4 bv = *(const float4*)(bi + lane*4);
    float4 y;
    y.x = (xv.x - mean)*rs*sv.x + bv.x;
    y.y = (xv.y - mean)*rs*sv.y + bv.y;
    y.z = (xv.z - mean)*rs*sv.z + bv.z;
    y.w = (xv.w - mean)*rs*sv.w + bv.w;
    *(float4*)(Y + (size_t)row * DD + lane*4) = y;
}

// ---------------------------------------------------------------------------
// Manual pooling: per (b,s) softmax over LM=36 of em@w, then weighted sum.
// ---------------------------------------------------------------------------
__global__ __launch_bounds__(256) void manual_pool(
    const float* __restrict__ em, const float* __restrict__ mk_w, const float* __restrict__ mk_b,
    const float* __restrict__ mv_w, const float* __restrict__ mv_b,
    float* __restrict__ MK, float* __restrict__ MV)
{
    int bs = blockIdx.x;
    const float* base = em + (size_t)bs * LMM * DD;
    __shared__ float ems[LMM][DD];
    __shared__ float wk_s[DD], wv_s[DD];
    __shared__ float sk[LMM], sv[LMM];
    __shared__ float inv2[2];
    int t = threadIdx.x;
    for (int i = t; i < LMM*DD/4; i += 256)
        ((float4*)&ems[0][0])[i] = ((const float4*)base)[i];
    wk_s[t] = mk_w[t];
    wv_s[t] = mv_w[t];
    __syncthreads();
    if (t < LMM) {
        float dk = 0.f, dv = 0.f;
        for (int d = 0; d < DD; ++d) {
            float e = ems[t][d];
            dk = fmaf(e, wk_s[d], dk);
            dv = fmaf(e, wv_s[d], dv);
        }
        sk[t] = dk + mk_b[0];
        sv[t] = dv + mv_b[0];
    }
    __syncthreads();
    if (t == 0) {
        float mk_ = -1e30f, mv_ = -1e30f;
        for (int l = 0; l < LMM; ++l) { mk_ = fmaxf(mk_, sk[l]); mv_ = fmaxf(mv_, sv[l]); }
        float sks = 0.f, svs = 0.f;
        for (int l = 0; l < LMM; ++l) {
            float ek = expf(sk[l]-mk_); sk[l] = ek; sks += ek;
            float ev = expf(sv[l]-mv_); sv[l] = ev; svs += ev;
        }
        inv2[0] = 1.f/sks; inv2[1] = 1.f/svs;
    }
    __syncthreads();
    float ak = 0.f, avv = 0.f;
    for (int l = 0; l < LMM; ++l) {
        float e = ems[l][t];
        ak  = fmaf(sk[l], e, ak);
        avv = fmaf(sv[l], e, avv);
    }
    MK[(size_t)bs*DD + t] = ak  * inv2[0];
    MV[(size_t)bs*DD + t] = avv * inv2[1];
}

// ---------------------------------------------------------------------------
__device__ __forceinline__ int qidx_to_t(int qi) {
    int blk = qi / 3, r = qi - blk*3;
    return blk*13 + (r == 0 ? 1 : (r == 1 ? 4 : 7));
}

__global__ void embed_kernel(const int* __restrict__ tokens,
    const float* __restrict__ emb_a, const float* __restrict__ emb_o,
    const float* __restrict__ pos, float* __restrict__ E, float* __restrict__ X)
{
    int idx = blockIdx.x * 256 + threadIdx.x;
    if (idx >= BT * 64) return;
    int row = idx >> 6;
    int c4 = (idx & 63) * 4;
    int tt = row % TT;
    int tok = tokens[row];
    const float* src = (tt % 13 == 0) ? (emb_a + tok * DD) : (emb_o + (size_t)tok * DD);
    float4 e = *(const float4*)(src + c4);
    float4 p = *(const float4*)(pos + (size_t)tt * DD + c4);
    *(float4*)(E + (size_t)row * DD + c4) = e;
    *(float4*)(X + (size_t)row * DD + c4) = make_float4(e.x+p.x, e.y+p.y, e.z+p.z, e.w+p.w);
}

__global__ void gather_q_kernel(const float* __restrict__ E, float* __restrict__ Qin)
{
    int idx = blockIdx.x * 256 + threadIdx.x;
    if (idx >= BB * NQ * 64) return;
    int row = idx >> 6, c4 = (idx & 63) * 4;
    int b = row / NQ, qi = row - b*NQ;
    int tt = qidx_to_t(qi);
    *(float4*)(Qin + (size_t)row*DD + c4) = *(const float4*)(E + ((size_t)b*TT + tt)*DD + c4);
}

__global__ void scatter_av_kernel(const float* __restrict__ AVp, float* __restrict__ X)
{
    int idx = blockIdx.x * 256 + threadIdx.x;
    if (idx >= BB * NQ * 64) return;
    int row = idx >> 6, c4 = (idx & 63)*4;
    int b = row / NQ, qi = row - b*NQ;
    int tt = qidx_to_t(qi);
    float* xp = X + ((size_t)b*TT + tt)*DD + c4;
    float4 a = *(const float4*)(AVp + (size_t)row*DD + c4);
    float4 xv = *(const float4*)xp;
    *(float4*)xp = make_float4(xv.x+a.x, xv.y+a.y, xv.z+a.z, xv.w+a.w);
}

__global__ void gather_h_kernel(const float* __restrict__ X, float* __restrict__ HX)
{
    int idx = blockIdx.x * 256 + threadIdx.x;
    if (idx >= BB * NHID * 64) return;
    int row = idx >> 6, c4 = (idx & 63)*4;
    int b = row / NHID, i = row - b*NHID;
    int tt = i*13 + 12;
    *(float4*)(HX + (size_t)row*DD + c4) = *(const float4*)(X + ((size_t)b*TT + tt)*DD + c4);
}

// 3-slot cross attention over manual keys/values; one wave per q-row
__global__ __launch_bounds__(256) void manual_attn(
    const float* __restrict__ Qm, const float* __restrict__ Kp,
    const float* __restrict__ Vp, float* __restrict__ AV)
{
    int row = blockIdx.x * 4 + (threadIdx.x >> 6);
    int lane = threadIdx.x & 63;
    int b = row / NQ;
    float4 q = *(const float4*)(Qm + (size_t)row * DD + lane*4);
    float s[3];
    #pragma unroll
    for (int j = 0; j < 3; ++j) {
        float4 kv = *(const float4*)(Kp + ((size_t)b*SS + j)*DD + lane*4);
        float d = q.x*kv.x + q.y*kv.y + q.z*kv.z + q.w*kv.w;
        #pragma unroll
        for (int m = 32; m; m >>= 1) d += __shfl_xor(d, m);
        s[j] = d * 0.0625f;   // 1/sqrt(256)
    }
    float mx = fmaxf(s[0], fmaxf(s[1], s[2]));
    float p0 = expf(s[0]-mx), p1 = expf(s[1]-mx), p2 = expf(s[2]-mx);
    float inv = 1.f/(p0+p1+p2);
    p0 *= inv; p1 *= inv; p2 *= inv;
    float4 v0 = *(const float4*)(Vp + ((size_t)b*SS+0)*DD + lane*4);
    float4 v1 = *(const float4*)(Vp + ((size_t)b*SS+1)*DD + lane*4);
    float4 v2 = *(const float4*)(Vp + ((size_t)b*SS+2)*DD + lane*4);
    float4 o;
    o.x = p0*v0.x + p1*v1.x + p2*v2.x;
    o.y = p0*v0.y + p1*v1.y + p2*v2.y;
    o.z = p0*v0.z + p1*v1.z + p2*v2.z;
    o.w = p0*v0.w + p1*v1.w + p2*v2.w;
    *(float4*)(AV + (size_t)row * DD + lane*4) = o;
}

// final head matmuls (N=5 and N=1) + softmax, one wave per row
__global__ __launch_bounds__(64) void head_final(
    const float* __restrict__ A2, const float* __restrict__ w3a, const float* __restrict__ b3a,
    const float* __restrict__ V2, const float* __restrict__ w3v, const float* __restrict__ b3v,
    float* __restrict__ out)
{
    int row = blockIdx.x;
    int lane = threadIdx.x;
    float4 a = *(const float4*)(A2 + (size_t)row*DD + lane*4);
    float lg[5];
    #pragma unroll
    for (int j = 0; j < 5; ++j) {
        float p = a.x*w3a[(lane*4+0)*5+j] + a.y*w3a[(lane*4+1)*5+j]
                + a.z*w3a[(lane*4+2)*5+j] + a.w*w3a[(lane*4+3)*5+j];
        #pragma unroll
        for (int m = 32; m; m >>= 1) p += __shfl_xor(p, m);
        lg[j] = p + b3a[j];
    }
    float4 v = *(const float4*)(V2 + (size_t)row*DD + lane*4);
    float pv = v.x*w3v[lane*4+0] + v.y*w3v[lane*4+1] + v.z*w3v[lane*4+2] + v.w*w3v[lane*4+3];
    #pragma unroll
    for (int m = 32; m; m >>= 1) pv += __shfl_xor(pv, m);
    if (lane == 0) {
        float mx = lg[0];
        #pragma unroll
        for (int j = 1; j < 5; ++j) mx = fmaxf(mx, lg[j]);
        float e[5], ssum = 0.f;
        #pragma unroll
        for (int j = 0; j < 5; ++j) { e[j] = expf(lg[j]-mx); ssum += e[j]; }
        float inv = 1.f/ssum;
        #pragma unroll
        for (int j = 0; j < 5; ++j) out[(size_t)row*5 + j] = e[j]*inv;
        out[(size_t)BB*NHID*5 + row] = pv + b3v[0];
    }
}

// ---------------------------------------------------------------------------
extern "C" void kernel_launch(void* const* d_in, const int* in_sizes, int n_in,
                              void* d_out, int out_size, void* d_ws, size_t ws_size,
                              hipStream_t stream)
{
    (void)in_sizes; (void)n_in; (void)out_size; (void)ws_size;
    const int*   tokens = (const int*)d_in[0];
    const float* em     = (const float*)d_in[1];
    const float* emb_a  = (const float*)d_in[2];
    const float* emb_o  = (const float*)d_in[3];
    const float* pos    = (const float*)d_in[4];
    const float* mk_w   = (const float*)d_in[5];
    const float* mk_b   = (const float*)d_in[6];
    const float* mv_w   = (const float*)d_in[7];
    const float* mv_b   = (const float*)d_in[8];
    const float* ma_wq  = (const float*)d_in[9];
    const float* ma_bq  = (const float*)d_in[10];
    const float* ma_wk  = (const float*)d_in[11];
    const float* ma_bk  = (const float*)d_in[12];
    const float* ma_wv  = (const float*)d_in[13];
    const float* ma_bv  = (const float*)d_in[14];
    const float* ma_wo  = (const float*)d_in[15];
    const float* ma_bo  = (const float*)d_in[16];
    const float* ln1_s  = (const float*)d_in[17];
    const float* ln1_b  = (const float*)d_in[18];
    const float* wq     = (const float*)d_in[19];
    const float* bq     = (const float*)d_in[20];
    const float* wk     = (const float*)d_in[21];
    const float* bk     = (const float*)d_in[22];
    const float* wv     = (const float*)d_in[23];
    const float* bv     = (const float*)d_in[24];
    const float* wo     = (const float*)d_in[25];
    const float* bo     = (const float*)d_in[26];
    const float* ln2_s  = (const float*)d_in[27];
    const float* ln2_b  = (const float*)d_in[28];
    const float* w1     = (const float*)d_in[29];
    const float* b1     = (const float*)d_in[30];
    const float* w2     = (const float*)d_in[31];
    const float* b2     = (const float*)d_in[32];
    const float* lnf_s  = (const float*)d_in[33];
    const float* lnf_b  = (const float*)d_in[34];
    const float* ha_w1  = (const float*)d_in[35];
    const float* ha_b1  = (const float*)d_in[36];
    const float* ha_w2  = (const float*)d_in[37];
    const float* ha_b2  = (const float*)d_in[38];
    const float* ha_w3  = (const float*)d_in[39];
    const float* ha_b3  = (const float*)d_in[40];
    const float* hv_w1  = (const float*)d_in[41];
    const float* hv_b1  = (const float*)d_in[42];
    const float* hv_w2  = (const float*)d_in[43];
    const float* hv_b2  = (const float*)d_in[44];
    const float* hv_w3  = (const float*)d_in[45];
    const float* hv_b3  = (const float*)d_in[46];

    float* ws = (float*)d_ws;
    size_t off = 0;
    const size_t SZ_XTD = (size_t)BT * DD;          // 6,815,744 floats
    float* E  = ws + off; off += SZ_XTD;
    float* X  = ws + off; off += SZ_XTD;
    float* Hb = ws + off; off += SZ_XTD;
    float* Qb = ws + off; off += SZ_XTD;
    float* Kb = ws + off; off += SZ_XTD;
    float* Vb = ws + off; off += SZ_XTD;
    float* Ob = ws + off; off += SZ_XTD;
    float* MKp = ws + off; off += BB*SS*DD;
    float* MVp = ws + off; off += BB*SS*DD;
    float* KP  = ws + off; off += BB*SS*DD;
    float* VP  = ws + off; off += BB*SS*DD;
    float* HX  = ws + off; off += BB*NHID*DD;
    float* HXN = ws + off; off += BB*NHID*DD;
    float* A1  = ws + off; off += BB*NHID*DD;
    float* A2  = ws + off; off += BB*NHID*DD;
    float* V1  = ws + off; off += BB*NHID*DD;
    float* V2  = ws + off; off += BB*NHID*DD;
    // aliases into dead regions:
    float* MID  = Qb;                                // spans Qb..Ob (BT*FF floats exactly)
    float* MQIN = Hb;                                // Hb unused until layer 0
    float* MQ   = Hb + (size_t)BB*NQ*DD;
    float* MAV  = Qb;                                // Qb unused until layer 0
    float* MAVP = Qb + (size_t)BB*NQ*DD;

    #define GEMM(ACT, RES, A_, W_, BIAS_, R_, C_, M_, N_, K_) \
        gemm_f32<ACT, RES><<<dim3(((M_)+63)/64, (N_)/64), 256, 0, stream>>>(A_, W_, BIAS_, R_, C_, M_, N_, K_)

    manual_pool<<<BB*SS, 256, 0, stream>>>(em, mk_w, mk_b, mv_w, mv_b, MKp, MVp);
    embed_kernel<<<(BT*64)/256, 256, 0, stream>>>(tokens, emb_a, emb_o, pos, E, X);
    gather_q_kernel<<<(BB*NQ*64)/256, 256, 0, stream>>>(E, MQIN);
    GEMM(0, false, MQIN, ma_wq, ma_bq, (const float*)nullptr, MQ, BB*NQ, DD, DD);
    GEMM(0, false, MKp,  ma_wk, ma_bk, (const float*)nullptr, KP, BB*SS, DD, DD);
    GEMM(0, false, MVp,  ma_wv, ma_bv, (const float*)nullptr, VP, BB*SS, DD, DD);
    manual_attn<<<(BB*NQ)/4, 256, 0, stream>>>(MQ, KP, VP, MAV);
    GEMM(0, false, MAV, ma_wo, ma_bo, (const float*)nullptr, MAVP, BB*NQ, DD, DD);
    scatter_av_kernel<<<(BB*NQ*64)/256, 256, 0, stream>>>(MAVP, X);

    for (int l = 0; l < NLAYER; ++l) {
        ln_kernel<<<BT/4, 256, 0, stream>>>(X, ln1_s + l*DD, ln1_b + l*DD, Hb, BT);
        GEMM(0, false, Hb, wq + (size_t)l*DD*DD, bq + l*DD, (const float*)nullptr, Qb, BT, DD, DD);
        GEMM(0, false, Hb, wk + (size_t)l*DD*DD, bk + l*DD, (const float*)nullptr, Kb, BT, DD, DD);
        GEMM(0, false, Hb, wv + (size_t)l*DD*DD, bv + l*DD, (const float*)nullptr, Vb, BT, DD, DD);
        attn_causal<<<dim3(TT/64, NH, BB), 256, 0, stream>>>(Qb, Kb, Vb, Ob);
        GEMM(0, true,  Ob, wo + (size_t)l*DD*DD, bo + l*DD, X, X, BT, DD, DD);
        ln_kernel<<<BT/4, 256, 0, stream>>>(X, ln2_s + l*DD, ln2_b + l*DD, Hb, BT);
        GEMM(1, false, Hb,  w1 + (size_t)l*DD*FF, b1 + l*FF, (const float*)nullptr, MID, BT, FF, DD);
        GEMM(0, true,  MID, w2 + (size_t)l*FF*DD, b2 + l*DD, X, X, BT, DD, FF);
    }

    gather_h_kernel<<<(BB*NHID*64)/256, 256, 0, stream>>>(X, HX);
    ln_kernel<<<(BB*NHID)/4, 256, 0, stream>>>(HX, lnf_s, lnf_b, HXN, BB*NHID);
    GEMM(2, false, HXN, ha_w1, ha_b1, (const float*)nullptr, A1, BB*NHID, DD, DD);
    GEMM(2, false, A1,  ha_w2, ha_b2, (const float*)nullptr, A2, BB*NHID, DD, DD);
    GEMM(2, false, HXN, hv_w1, hv_b1, (const float*)nullptr, V1, BB*NHID, DD, DD);
    GEMM(2, false, V1,  hv_w2, hv_b2, (const float*)nullptr, V2, BB*NHID, DD, DD);
    head_final<<<BB*NHID, 64, 0, stream>>>(A2, ha_w3, ha_b3, V2, hv_w3, hv_b3, (float*)d_out);
    #undef GEMM
}

// Round 2
// 908.437 us; speedup vs baseline: 4.3194x; 4.3194x over previous
//
#include <hip/hip_runtime.h>
#include <math.h>

#define BB 32
#define TT 832
#define DD 256
#define NLAYER 4
#define NH 4
#define HDIM 64
#define FF 1024
#define SS 3
#define LMM 36
#define BT (BB*TT)      // 26624
#define NQ 192
#define NHID 64

typedef unsigned short u16;
typedef __attribute__((ext_vector_type(8))) short bf16x8;   // 8 bf16 (4 VGPR)
typedef __attribute__((ext_vector_type(4))) float f32x4;    // 4 fp32

__device__ __forceinline__ u16 f2bf(float f) {
    unsigned u = __builtin_bit_cast(unsigned, f);
    unsigned r = (u + 0x7fffu + ((u >> 16) & 1u)) >> 16;
    return (u16)r;
}

__device__ __forceinline__ void gload_lds16(const void* g, void* l) {
    __builtin_amdgcn_global_load_lds(
        (const __attribute__((address_space(1))) unsigned int*)g,
        (__attribute__((address_space(3))) unsigned int*)l, 16, 0, 0);
}

static __device__ __forceinline__ float gelu_tanh(float x) {
    float z = 0.7978845608028654f * (x + 0.044715f * x * x * x);
    float t = 1.f - 2.f / (1.f + __expf(2.f * z));
    return 0.5f * x * (1.f + t);
}

// ---------------------------------------------------------------------------
// Weight convert+transpose: src f32 [L][K][N] -> dst bf16 [L][nrows][K] at row0
// grid (N/32, K/32, L), 256 threads
// ---------------------------------------------------------------------------
__global__ __launch_bounds__(256) void wtrans(const float* __restrict__ src,
    u16* __restrict__ dst, int K, int N, int row0, int nrows)
{
    __shared__ float tile[32][33];
    int n0 = blockIdx.x * 32, k0 = blockIdx.y * 32, l = blockIdx.z;
    const float* s = src + (size_t)l * K * N;
    u16* d = dst + (size_t)l * nrows * K;
    int t = threadIdx.x;
    int r = t >> 3, c4 = (t & 7) * 4;
    float4 v = *(const float4*)(s + (size_t)(k0 + r) * N + n0 + c4);
    tile[r][c4+0] = v.x; tile[r][c4+1] = v.y; tile[r][c4+2] = v.z; tile[r][c4+3] = v.w;
    __syncthreads();
    int nr = t >> 3, kc4 = (t & 7) * 4;
    ushort4 o;
    o.x = f2bf(tile[kc4+0][nr]); o.y = f2bf(tile[kc4+1][nr]);
    o.z = f2bf(tile[kc4+2][nr]); o.w = f2bf(tile[kc4+3][nr]);
    *(ushort4*)(d + (size_t)(row0 + n0 + nr) * K + k0 + kc4) = o;
}

__global__ void concat_bias(const float* __restrict__ bq, const float* __restrict__ bk,
    const float* __restrict__ bv, float* __restrict__ bqkv)
{
    int i = blockIdx.x * 256 + threadIdx.x;   // NL*768
    int l = i / 768, j = i - l * 768;
    float v;
    if (j < 256) v = bq[l*256 + j];
    else if (j < 512) v = bk[l*256 + j - 256];
    else v = bv[l*256 + j - 512];
    bqkv[i] = v;
}

// ---------------------------------------------------------------------------
// bf16 MFMA GEMM: C[M,N] = act(A[M,K]@W + bias) (+res). Wt is [N][K] bf16.
// 128x128 tile, BK=64, 4 waves (2x2), 16x16x32 mfma, swizzled LDS.
// M, N multiples of 128; K multiple of 64.
// ---------------------------------------------------------------------------
template<int ACT, int RES, int OUTBF>
__global__ __launch_bounds__(256) void gemm_bf16(
    const u16* __restrict__ A, int lda,
    const u16* __restrict__ Wt,
    const float* __restrict__ bias,
    const float* __restrict__ Rsd,
    void* __restrict__ Cout, int ldc, int K)
{
    __shared__ u16 As[128*64];
    __shared__ u16 Bs[128*64];
    const int t = threadIdx.x, w = t >> 6;
    const int lane = t & 63, lo = lane & 15, hi = lane >> 4;
    const int bm = blockIdx.x * 128, bn = blockIdx.y * 128;
    const int wr = w >> 1, wc = w & 1;
    f32x4 acc[4][4] = {};

    for (int k0 = 0; k0 < K; k0 += 64) {
        __syncthreads();
        #pragma unroll
        for (int i = 0; i < 4; ++i) {
            int id = i*256 + t;
            int row = id >> 3, c = id & 7, cs = c ^ (row & 7);
            gload_lds16(A + (size_t)(bm + row) * lda + k0 + cs*8,
                        &As[(i*256 + w*64)*8]);
            gload_lds16(Wt + (size_t)(bn + row) * K + k0 + cs*8,
                        &Bs[(i*256 + w*64)*8]);
        }
        __syncthreads();
        #pragma unroll
        for (int ks = 0; ks < 2; ++ks) {
            bf16x8 af[4], bfr[4];
            #pragma unroll
            for (int m = 0; m < 4; ++m) {
                int row = wr*64 + m*16 + lo;
                af[m] = *(const bf16x8*)&As[row*64 + (((ks*4 + hi) ^ (row & 7)) * 8)];
            }
            #pragma unroll
            for (int n = 0; n < 4; ++n) {
                int row = wc*64 + n*16 + lo;
                bfr[n] = *(const bf16x8*)&Bs[row*64 + (((ks*4 + hi) ^ (row & 7)) * 8)];
            }
            #pragma unroll
            for (int m = 0; m < 4; ++m)
                #pragma unroll
                for (int n = 0; n < 4; ++n)
                    acc[m][n] = __builtin_amdgcn_mfma_f32_16x16x32_bf16(
                        af[m], bfr[n], acc[m][n], 0, 0, 0);
        }
    }
    float bv[4];
    #pragma unroll
    for (int n = 0; n < 4; ++n) bv[n] = bias[bn + wc*64 + n*16 + lo];
    #pragma unroll
    for (int m = 0; m < 4; ++m) {
        #pragma unroll
        for (int r = 0; r < 4; ++r) {
            int grow = bm + wr*64 + m*16 + hi*4 + r;
            #pragma unroll
            for (int n = 0; n < 4; ++n) {
                int gcol = bn + wc*64 + n*16 + lo;
                float v = acc[m][n][r] + bv[n];
                if (ACT == 1) v = gelu_tanh(v);
                if (ACT == 2) v = (v > 0.f) ? v : 0.01f * v;
                size_t off = (size_t)grow * ldc + gcol;
                if (RES) v += Rsd[off];
                if (OUTBF) ((u16*)Cout)[off] = f2bf(v);
                else       ((float*)Cout)[off] = v;
            }
        }
    }
}

// ---------------------------------------------------------------------------
// V transpose per layer: QKV[:,512+h*64+d] -> Vt[b][h][d][t]   (bf16)
// grid (T/64, H, B), 256 threads
// ---------------------------------------------------------------------------
__global__ __launch_bounds__(256) void transpose_v(const u16* __restrict__ QKV,
    u16* __restrict__ Vt)
{
    int tt = blockIdx.x, h = blockIdx.y, b = blockIdx.z;
    __shared__ u16 Vs2[64][72];
    int id = threadIdx.x;
    int tr = id >> 2, dc = (id & 3) * 16;
    const u16* src = QKV + ((size_t)(b*TT + tt*64 + tr)) * 768 + 512 + h*64 + dc;
    *(uint4*)&Vs2[tr][dc]     = *(const uint4*)src;
    *(uint4*)&Vs2[tr][dc + 8] = *(const uint4*)(src + 8);
    __syncthreads();
    int d = id >> 2, tc = (id & 3) * 16;
    u16 tmp[16];
    #pragma unroll
    for (int j = 0; j < 16; ++j) tmp[j] = Vs2[tc + j][d];
    u16* dst = Vt + ((size_t)(b*NH + h) * 64 + d) * TT + tt*64 + tc;
    *(uint4*)dst       = *(uint4*)&tmp[0];
    *(uint4*)&dst[8]   = *(uint4*)&tmp[8];
}

// ---------------------------------------------------------------------------
// MFMA flash attention. grid (T/64, H, B), 4 waves; swapped QK^T (T12).
// QKV bf16 [BT][768]; Vt bf16 [B][H][64][T]; O bf16 [BT][256].
// ---------------------------------------------------------------------------
__global__ __launch_bounds__(256) void attn_mfma(
    const u16* __restrict__ QKV, const u16* __restrict__ Vt,
    u16* __restrict__ O)
{
    const int qt = blockIdx.x, h = blockIdx.y, b = blockIdx.z;
    __shared__ u16 Ks[64*64];
    __shared__ u16 Vts[64*64];
    __shared__ u16 Plds[4][16*64];
    const int t = threadIdx.x, w = t >> 6;
    const int lane = t & 63, lo = lane & 15, hi = lane >> 4;

    bf16x8 qf[2];
    {
        const u16* qp = QKV + ((size_t)(b*TT + qt*64 + w*16 + lo)) * 768 + h*64 + hi*8;
        qf[0] = *(const bf16x8*)qp;
        qf[1] = *(const bf16x8*)(qp + 32);
    }
    f32x4 oacc[4] = {};
    float mrow = -1e30f, lrow = 0.f;

    for (int kt = 0; kt <= qt; ++kt) {
        __syncthreads();
        #pragma unroll
        for (int i = 0; i < 2; ++i) {
            int id = i*256 + t;
            int row = id >> 3, c = id & 7, cs = c ^ (row & 7);
            gload_lds16(QKV + ((size_t)(b*TT + kt*64 + row)) * 768 + 256 + h*64 + cs*8,
                        &Ks[(i*256 + w*64)*8]);
            gload_lds16(Vt + ((size_t)(b*NH + h) * 64 + row) * TT + kt*64 + cs*8,
                        &Vts[(i*256 + w*64)*8]);
        }
        __syncthreads();
        // swapped QK^T: sacc[mf] holds S[key = mf*16+hi*4+r][q = lo]
        f32x4 sacc[4] = {};
        #pragma unroll
        for (int ks = 0; ks < 2; ++ks) {
            #pragma unroll
            for (int mf = 0; mf < 4; ++mf) {
                int row = mf*16 + lo;
                bf16x8 kf = *(const bf16x8*)&Ks[row*64 + (((ks*4 + hi) ^ (row & 7)) * 8)];
                sacc[mf] = __builtin_amdgcn_mfma_f32_16x16x32_bf16(kf, qf[ks], sacc[mf], 0, 0, 0);
            }
        }
        float p[4][4];
        float pmax = -1e30f;
        #pragma unroll
        for (int mf = 0; mf < 4; ++mf)
            #pragma unroll
            for (int r = 0; r < 4; ++r) {
                float s = sacc[mf][r] * 0.125f;
                if (kt == qt) {
                    int key = mf*16 + hi*4 + r;
                    int q = w*16 + lo;
                    if (key > q) s = -1e9f;
                }
                p[mf][r] = s;
                pmax = fmaxf(pmax, s);
            }
        pmax = fmaxf(pmax, __shfl_xor(pmax, 16));
        pmax = fmaxf(pmax, __shfl_xor(pmax, 32));
        float mnew = fmaxf(mrow, pmax);
        float alpha = __expf(mrow - mnew);
        mrow = mnew;
        float rsum = 0.f;
        #pragma unroll
        for (int mf = 0; mf < 4; ++mf)
            #pragma unroll
            for (int r = 0; r < 4; ++r) {
                float e = __expf(p[mf][r] - mnew);
                p[mf][r] = e;
                rsum += e;
            }
        rsum += __shfl_xor(rsum, 16);
        rsum += __shfl_xor(rsum, 32);
        lrow = lrow * alpha + rsum;
        // pack P -> Plds[w] (q=lo rows, swizzled pairs)
        {
            unsigned* PW = (unsigned*)&Plds[w][0];
            #pragma unroll
            for (int mf = 0; mf < 4; ++mf) {
                int c = mf*2 + (hi >> 1);
                int base = lo*32 + ((c ^ (lo & 7)) * 4) + (hi & 1) * 2;
                PW[base]     = (unsigned)f2bf(p[mf][0]) | ((unsigned)f2bf(p[mf][1]) << 16);
                PW[base + 1] = (unsigned)f2bf(p[mf][2]) | ((unsigned)f2bf(p[mf][3]) << 16);
            }
        }
        float al[4];
        #pragma unroll
        for (int r = 0; r < 4; ++r) al[r] = __shfl(alpha, hi*4 + r);
        #pragma unroll
        for (int n = 0; n < 4; ++n) {
            oacc[n][0] *= al[0]; oacc[n][1] *= al[1];
            oacc[n][2] *= al[2]; oacc[n][3] *= al[3];
        }
        // PV
        #pragma unroll
        for (int ks = 0; ks < 2; ++ks) {
            bf16x8 pf = *(const bf16x8*)&Plds[w][lo*64 + (((ks*4 + hi) ^ (lo & 7)) * 8)];
            #pragma unroll
            for (int n = 0; n < 4; ++n) {
                int d = n*16 + lo;
                bf16x8 vf = *(const bf16x8*)&Vts[d*64 + (((ks*4 + hi) ^ (d & 7)) * 8)];
                oacc[n] = __builtin_amdgcn_mfma_f32_16x16x32_bf16(pf, vf, oacc[n], 0, 0, 0);
            }
        }
    }
    float linv[4];
    #pragma unroll
    for (int r = 0; r < 4; ++r) linv[r] = 1.0f / __shfl(lrow, hi*4 + r);
    #pragma unroll
    for (int n = 0; n < 4; ++n)
        #pragma unroll
        for (int r = 0; r < 4; ++r) {
            size_t row = (size_t)(b*TT + qt*64 + w*16 + hi*4 + r);
            O[row*256 + h*64 + n*16 + lo] = f2bf(oacc[n][r] * linv[r]);
        }
}

// ---------------------------------------------------------------------------
// fp32 GEMM (small matrices only). ACT: 0 none, 2 leaky
// ---------------------------------------------------------------------------
template<int ACT, bool RES>
__global__ __launch_bounds__(256) void gemm_f32(
    const float* __restrict__ A, const float* __restrict__ W,
    const float* __restrict__ bias, const float* __restrict__ Rsd,
    float* __restrict__ C, int M, int N, int K)
{
    __shared__ float As[16][68];
    __shared__ float Ws[16][68];
    const int bm = blockIdx.x * 64;
    const int bn = blockIdx.y * 64;
    const int t = threadIdx.x;
    const int tx = t & 15, ty = t >> 4;
    float c[4][4] = {};
    for (int k0 = 0; k0 < K; k0 += 16) {
        {
            int row = bm + (t >> 2);
            int kk = (t & 3) * 4;
            float4 a = make_float4(0.f, 0.f, 0.f, 0.f);
            if (row < M) a = *(const float4*)(A + (size_t)row * K + k0 + kk);
            int mm = t >> 2;
            As[kk+0][mm] = a.x; As[kk+1][mm] = a.y; As[kk+2][mm] = a.z; As[kk+3][mm] = a.w;
        }
        {
            int kr = t >> 4;
            int col = (t & 15) * 4;
            *(float4*)&Ws[kr][col] = *(const float4*)(W + (size_t)(k0 + kr) * N + bn + col);
        }
        __syncthreads();
        #pragma unroll
        for (int kk = 0; kk < 16; ++kk) {
            float4 a4 = *(const float4*)&As[kk][ty*4];
            float4 b4 = *(const float4*)&Ws[kk][tx*4];
            float av[4] = {a4.x, a4.y, a4.z, a4.w};
            float bb[4] = {b4.x, b4.y, b4.z, b4.w};
            #pragma unroll
            for (int i = 0; i < 4; ++i)
                #pragma unroll
                for (int j = 0; j < 4; ++j)
                    c[i][j] = fmaf(av[i], bb[j], c[i][j]);
        }
        __syncthreads();
    }
    float4 b4 = *(const float4*)(bias + bn + tx*4);
    float bvals[4] = {b4.x, b4.y, b4.z, b4.w};
    #pragma unroll
    for (int i = 0; i < 4; ++i) {
        int row = bm + ty*4 + i;
        if (row >= M) continue;
        float tmp[4];
        #pragma unroll
        for (int j = 0; j < 4; ++j) {
            float v = c[i][j] + bvals[j];
            if (ACT == 2) v = (v > 0.f) ? v : 0.01f * v;
            tmp[j] = v;
        }
        size_t off = (size_t)row * N + bn + tx*4;
        if (RES) {
            float4 r4 = *(const float4*)(Rsd + off);
            tmp[0] += r4.x; tmp[1] += r4.y; tmp[2] += r4.z; tmp[3] += r4.w;
        }
        *(float4*)(C + off) = make_float4(tmp[0], tmp[1], tmp[2], tmp[3]);
    }
}

// ---------------------------------------------------------------------------
// LayerNorm: fp32 in, bf16 or fp32 out
// ---------------------------------------------------------------------------
template<int OUTBF>
__global__ __launch_bounds__(256) void ln_kernel(const float* __restrict__ Xin,
    const float* __restrict__ sc, const float* __restrict__ bi,
    void* __restrict__ Y, int M)
{
    int row = blockIdx.x * 4 + (threadIdx.x >> 6);
    if (row >= M) return;
    int lane = threadIdx.x & 63;
    float4 xv = *(const float4*)(Xin + (size_t)row * DD + lane*4);
    float sum = xv.x + xv.y + xv.z + xv.w;
    float sq  = xv.x*xv.x + xv.y*xv.y + xv.z*xv.z + xv.w*xv.w;
    #pragma unroll
    for (int m = 32; m; m >>= 1) { sum += __shfl_xor(sum, m); sq += __shfl_xor(sq, m); }
    float mean = sum * (1.f/256.f);
    float var  = sq * (1.f/256.f) - mean*mean;
    float rs = rsqrtf(var + 1e-5f);
    float4 sv = *(const float4*)(sc + lane*4);
    float4 bv = *(const float4*)(bi + lane*4);
    float4 y;
    y.x = (xv.x - mean)*rs*sv.x + bv.x;
    y.y = (xv.y - mean)*rs*sv.y + bv.y;
    y.z = (xv.z - mean)*rs*sv.z + bv.z;
    y.w = (xv.w - mean)*rs*sv.w + bv.w;
    if (OUTBF) {
        ushort4 o; o.x = f2bf(y.x); o.y = f2bf(y.y); o.z = f2bf(y.z); o.w = f2bf(y.w);
        *(ushort4*)((u16*)Y + (size_t)row * DD + lane*4) = o;
    } else {
        *(float4*)((float*)Y + (size_t)row * DD + lane*4) = y;
    }
}

// ---------------------------------------------------------------------------
__global__ __launch_bounds__(256) void manual_pool(
    const float* __restrict__ em, const float* __restrict__ mk_w, const float* __restrict__ mk_b,
    const float* __restrict__ mv_w, const float* __restrict__ mv_b,
    float* __restrict__ MK, float* __restrict__ MV)
{
    int bs = blockIdx.x;
    const float* base = em + (size_t)bs * LMM * DD;
    __shared__ float ems[LMM][DD];
    __shared__ float wk_s[DD], wv_s[DD];
    __shared__ float sk[LMM], sv[LMM];
    __shared__ float inv2[2];
    int t = threadIdx.x;
    for (int i = t; i < LMM*DD/4; i += 256)
        ((float4*)&ems[0][0])[i] = ((const float4*)base)[i];
    wk_s[t] = mk_w[t];
    wv_s[t] = mv_w[t];
    __syncthreads();
    if (t < LMM) {
        float dk = 0.f, dv = 0.f;
        for (int d = 0; d < DD; ++d) {
            float e = ems[t][d];
            dk = fmaf(e, wk_s[d], dk);
            dv = fmaf(e, wv_s[d], dv);
        }
        sk[t] = dk + mk_b[0];
        sv[t] = dv + mv_b[0];
    }
    __syncthreads();
    if (t == 0) {
        float mk_ = -1e30f, mv_ = -1e30f;
        for (int l = 0; l < LMM; ++l) { mk_ = fmaxf(mk_, sk[l]); mv_ = fmaxf(mv_, sv[l]); }
        float sks = 0.f, svs = 0.f;
        for (int l = 0; l < LMM; ++l) {
            float ek = expf(sk[l]-mk_); sk[l] = ek; sks += ek;
            float ev = expf(sv[l]-mv_); sv[l] = ev; svs += ev;
        }
        inv2[0] = 1.f/sks; inv2[1] = 1.f/svs;
    }
    __syncthreads();
    float ak = 0.f, avv = 0.f;
    for (int l = 0; l < LMM; ++l) {
        float e = ems[l][t];
        ak  = fmaf(sk[l], e, ak);
        avv = fmaf(sv[l], e, avv);
    }
    MK[(size_t)bs*DD + t] = ak  * inv2[0];
    MV[(size_t)bs*DD + t] = avv * inv2[1];
}

__device__ __forceinline__ int qidx_to_t(int qi) {
    int blk = qi / 3, r = qi - blk*3;
    return blk*13 + (r == 0 ? 1 : (r == 1 ? 4 : 7));
}

__global__ void embed_kernel(const int* __restrict__ tokens,
    const float* __restrict__ emb_a, const float* __restrict__ emb_o,
    const float* __restrict__ pos, float* __restrict__ E, float* __restrict__ X)
{
    int idx = blockIdx.x * 256 + threadIdx.x;
    if (idx >= BT * 64) return;
    int row = idx >> 6;
    int c4 = (idx & 63) * 4;
    int tt = row % TT;
    int tok = tokens[row];
    const float* src = (tt % 13 == 0) ? (emb_a + tok * DD) : (emb_o + (size_t)tok * DD);
    float4 e = *(const float4*)(src + c4);
    float4 p = *(const float4*)(pos + (size_t)tt * DD + c4);
    *(float4*)(E + (size_t)row * DD + c4) = e;
    *(float4*)(X + (size_t)row * DD + c4) = make_float4(e.x+p.x, e.y+p.y, e.z+p.z, e.w+p.w);
}

__global__ void gather_q_kernel(const float* __restrict__ E, float* __restrict__ Qin)
{
    int idx = blockIdx.x * 256 + threadIdx.x;
    if (idx >= BB * NQ * 64) return;
    int row = idx >> 6, c4 = (idx & 63) * 4;
    int b = row / NQ, qi = row - b*NQ;
    int tt = qidx_to_t(qi);
    *(float4*)(Qin + (size_t)row*DD + c4) = *(const float4*)(E + ((size_t)b*TT + tt)*DD + c4);
}

__global__ void scatter_av_kernel(const float* __restrict__ AVp, float* __restrict__ X)
{
    int idx = blockIdx.x * 256 + threadIdx.x;
    if (idx >= BB * NQ * 64) return;
    int row = idx >> 6, c4 = (idx & 63)*4;
    int b = row / NQ, qi = row - b*NQ;
    int tt = qidx_to_t(qi);
    float* xp = X + ((size_t)b*TT + tt)*DD + c4;
    float4 a = *(const float4*)(AVp + (size_t)row*DD + c4);
    float4 xv = *(const float4*)xp;
    *(float4*)xp = make_float4(xv.x+a.x, xv.y+a.y, xv.z+a.z, xv.w+a.w);
}

__global__ void gather_h_kernel(const float* __restrict__ X, float* __restrict__ HX)
{
    int idx = blockIdx.x * 256 + threadIdx.x;
    if (idx >= BB * NHID * 64) return;
    int row = idx >> 6, c4 = (idx & 63)*4;
    int b = row / NHID, i = row - b*NHID;
    int tt = i*13 + 12;
    *(float4*)(HX + (size_t)row*DD + c4) = *(const float4*)(X + ((size_t)b*TT + tt)*DD + c4);
}

__global__ __launch_bounds__(256) void manual_attn(
    const float* __restrict__ Qm, const float* __restrict__ Kp,
    const float* __restrict__ Vp, float* __restrict__ AV)
{
    int row = blockIdx.x * 4 + (threadIdx.x >> 6);
    int lane = threadIdx.x & 63;
    int b = row / NQ;
    float4 q = *(const float4*)(Qm + (size_t)row * DD + lane*4);
    float s[3];
    #pragma unroll
    for (int j = 0; j < 3; ++j) {
        float4 kv = *(const float4*)(Kp + ((size_t)b*SS + j)*DD + lane*4);
        float d = q.x*kv.x + q.y*kv.y + q.z*kv.z + q.w*kv.w;
        #pragma unroll
        for (int m = 32; m; m >>= 1) d += __shfl_xor(d, m);
        s[j] = d * 0.0625f;
    }
    float mx = fmaxf(s[0], fmaxf(s[1], s[2]));
    float p0 = expf(s[0]-mx), p1 = expf(s[1]-mx), p2 = expf(s[2]-mx);
    float inv = 1.f/(p0+p1+p2);
    p0 *= inv; p1 *= inv; p2 *= inv;
    float4 v0 = *(const float4*)(Vp + ((size_t)b*SS+0)*DD + lane*4);
    float4 v1 = *(const float4*)(Vp + ((size_t)b*SS+1)*DD + lane*4);
    float4 v2 = *(const float4*)(Vp + ((size_t)b*SS+2)*DD + lane*4);
    float4 o;
    o.x = p0*v0.x + p1*v1.x + p2*v2.x;
    o.y = p0*v0.y + p1*v1.y + p2*v2.y;
    o.z = p0*v0.z + p1*v1.z + p2*v2.z;
    o.w = p0*v0.w + p1*v1.w + p2*v2.w;
    *(float4*)(AV + (size_t)row * DD + lane*4) = o;
}

__global__ __launch_bounds__(64) void head_final(
    const float* __restrict__ A2, const float* __restrict__ w3a, const float* __restrict__ b3a,
    const float* __restrict__ V2, const float* __restrict__ w3v, const float* __restrict__ b3v,
    float* __restrict__ out)
{
    int row = blockIdx.x;
    int lane = threadIdx.x;
    float4 a = *(const float4*)(A2 + (size_t)row*DD + lane*4);
    float lg[5];
    #pragma unroll
    for (int j = 0; j < 5; ++j) {
        float p = a.x*w3a[(lane*4+0)*5+j] + a.y*w3a[(lane*4+1)*5+j]
                + a.z*w3a[(lane*4+2)*5+j] + a.w*w3a[(lane*4+3)*5+j];
        #pragma unroll
        for (int m = 32; m; m >>= 1) p += __shfl_xor(p, m);
        lg[j] = p + b3a[j];
    }
    float4 v = *(const float4*)(V2 + (size_t)row*DD + lane*4);
    float pv = v.x*w3v[lane*4+0] + v.y*w3v[lane*4+1] + v.z*w3v[lane*4+2] + v.w*w3v[lane*4+3];
    #pragma unroll
    for (int m = 32; m; m >>= 1) pv += __shfl_xor(pv, m);
    if (lane == 0) {
        float mx = lg[0];
        #pragma unroll
        for (int j = 1; j < 5; ++j) mx = fmaxf(mx, lg[j]);
        float e[5], ssum = 0.f;
        #pragma unroll
        for (int j = 0; j < 5; ++j) { e[j] = expf(lg[j]-mx); ssum += e[j]; }
        float inv = 1.f/ssum;
        #pragma unroll
        for (int j = 0; j < 5; ++j) out[(size_t)row*5 + j] = e[j]*inv;
        out[(size_t)BB*NHID*5 + row] = pv + b3v[0];
    }
}

// ---------------------------------------------------------------------------
extern "C" void kernel_launch(void* const* d_in, const int* in_sizes, int n_in,
                              void* d_out, int out_size, void* d_ws, size_t ws_size,
                              hipStream_t stream)
{
    (void)in_sizes; (void)n_in; (void)out_size; (void)ws_size;
    const int*   tokens = (const int*)d_in[0];
    const float* em     = (const float*)d_in[1];
    const float* emb_a  = (const float*)d_in[2];
    const float* emb_o  = (const float*)d_in[3];
    const float* pos    = (const float*)d_in[4];
    const float* mk_w   = (const float*)d_in[5];
    const float* mk_b   = (const float*)d_in[6];
    const float* mv_w   = (const float*)d_in[7];
    const float* mv_b   = (const float*)d_in[8];
    const float* ma_wq  = (const float*)d_in[9];
    const float* ma_bq  = (const float*)d_in[10];
    const float* ma_wk  = (const float*)d_in[11];
    const float* ma_bk  = (const float*)d_in[12];
    const float* ma_wv  = (const float*)d_in[13];
    const float* ma_bv  = (const float*)d_in[14];
    const float* ma_wo  = (const float*)d_in[15];
    const float* ma_bo  = (const float*)d_in[16];
    const float* ln1_s  = (const float*)d_in[17];
    const float* ln1_b  = (const float*)d_in[18];
    const float* wq     = (const float*)d_in[19];
    const float* bq     = (const float*)d_in[20];
    const float* wk     = (const float*)d_in[21];
    const float* bk     = (const float*)d_in[22];
    const float* wv     = (const float*)d_in[23];
    const float* bv     = (const float*)d_in[24];
    const float* wo     = (const float*)d_in[25];
    const float* bo     = (const float*)d_in[26];
    const float* ln2_s  = (const float*)d_in[27];
    const float* ln2_b  = (const float*)d_in[28];
    const float* w1     = (const float*)d_in[29];
    const float* b1     = (const float*)d_in[30];
    const float* w2     = (const float*)d_in[31];
    const float* b2     = (const float*)d_in[32];
    const float* lnf_s  = (const float*)d_in[33];
    const float* lnf_b  = (const float*)d_in[34];
    const float* ha_w1  = (const float*)d_in[35];
    const float* ha_b1  = (const float*)d_in[36];
    const float* ha_w2  = (const float*)d_in[37];
    const float* ha_b2  = (const float*)d_in[38];
    const float* ha_w3  = (const float*)d_in[39];
    const float* ha_b3  = (const float*)d_in[40];
    const float* hv_w1  = (const float*)d_in[41];
    const float* hv_b1  = (const float*)d_in[42];
    const float* hv_w2  = (const float*)d_in[43];
    const float* hv_b2  = (const float*)d_in[44];
    const float* hv_w3  = (const float*)d_in[45];
    const float* hv_b3  = (const float*)d_in[46];

    char* base = (char*)d_ws;
    const size_t OFF_X    = 0;
    const size_t OFF_HB   = 27262976;   // X: BT*256*4
    const size_t OFF_QKV  = 40894464;   // Hb: BT*256*2
    const size_t OFF_VT   = 81788928;   // QKV: BT*768*2
    const size_t OFF_OB   = 95420416;   // Vt: 32*4*64*832*2
    const size_t OFF_MID  = 109051904;  // Ob: BT*256*2
    const size_t OFF_W    = 163577856;  // MID: BT*1024*2

    float* X    = (float*)(base + OFF_X);
    u16*   Hb   = (u16*)(base + OFF_HB);
    u16*   QKVb = (u16*)(base + OFF_QKV);
    u16*   Vt   = (u16*)(base + OFF_VT);
    u16*   Ob   = (u16*)(base + OFF_OB);
    u16*   MID  = (u16*)(base + OFF_MID);
    u16*   Wqkv = (u16*)(base + OFF_W);                 // [NL][768][256]
    u16*   Wo   = Wqkv + (size_t)NLAYER*768*256;        // [NL][256][256]
    u16*   W1t  = Wo   + (size_t)NLAYER*256*256;        // [NL][1024][256]
    u16*   W2t  = W1t  + (size_t)NLAYER*1024*256;       // [NL][256][1024]
    float* bqkv = (float*)(W2t + (size_t)NLAYER*256*1024);  // [NL][768]

    // aliases into regions that are dead during pre/post stages:
    float* E    = (float*)(base + OFF_QKV);             // 27.3MB <= 40.9MB
    float* MQIN = (float*)(base + OFF_MID);
    float* MQ   = MQIN + (size_t)BB*NQ*DD;
    float* MAV  = MQ   + (size_t)BB*NQ*DD;
    float* MAVP = MAV  + (size_t)BB*NQ*DD;
    float* MKp  = (float*)(base + OFF_VT);
    float* MVp  = MKp + BB*SS*DD;
    float* KP   = MVp + BB*SS*DD;
    float* VP   = KP  + BB*SS*DD;
    float* HX   = (float*)(base + OFF_MID);             // post-stage (MID dead)
    float* HXN  = HX  + (size_t)BB*NHID*DD;
    float* A1   = HXN + (size_t)BB*NHID*DD;
    float* A2   = A1  + (size_t)BB*NHID*DD;
    float* V1   = A2  + (size_t)BB*NHID*DD;
    float* V2   = V1  + (size_t)BB*NHID*DD;

    // ---- weight conversion (bf16, transposed) ----
    wtrans<<<dim3(8, 8, NLAYER), 256, 0, stream>>>(wq, Wqkv, 256, 256, 0,   768);
    wtrans<<<dim3(8, 8, NLAYER), 256, 0, stream>>>(wk, Wqkv, 256, 256, 256, 768);
    wtrans<<<dim3(8, 8, NLAYER), 256, 0, stream>>>(wv, Wqkv, 256, 256, 512, 768);
    wtrans<<<dim3(8, 8, NLAYER), 256, 0, stream>>>(wo, Wo,   256, 256, 0,   256);
    wtrans<<<dim3(32, 8, NLAYER), 256, 0, stream>>>(w1, W1t, 256, 1024, 0, 1024);
    wtrans<<<dim3(8, 32, NLAYER), 256, 0, stream>>>(w2, W2t, 1024, 256, 0,  256);
    concat_bias<<<12, 256, 0, stream>>>(bq, bk, bv, bqkv);

    #define GEMMF(ACT, RES, A_, W_, BIAS_, R_, C_, M_, N_, K_) \
        gemm_f32<ACT, RES><<<dim3(((M_)+63)/64, (N_)/64), 256, 0, stream>>>(A_, W_, BIAS_, R_, C_, M_, N_, K_)

    // ---- pre-stage (fp32) ----
    manual_pool<<<BB*SS, 256, 0, stream>>>(em, mk_w, mk_b, mv_w, mv_b, MKp, MVp);
    embed_kernel<<<(BT*64)/256, 256, 0, stream>>>(tokens, emb_a, emb_o, pos, E, X);
    gather_q_kernel<<<(BB*NQ*64)/256, 256, 0, stream>>>(E, MQIN);
    GEMMF(0, false, MQIN, ma_wq, ma_bq, (const float*)nullptr, MQ, BB*NQ, DD, DD);
    GEMMF(0, false, MKp,  ma_wk, ma_bk, (const float*)nullptr, KP, BB*SS, DD, DD);
    GEMMF(0, false, MVp,  ma_wv, ma_bv, (const float*)nullptr, VP, BB*SS, DD, DD);
    manual_attn<<<(BB*NQ)/4, 256, 0, stream>>>(MQ, KP, VP, MAV);
    GEMMF(0, false, MAV, ma_wo, ma_bo, (const float*)nullptr, MAVP, BB*NQ, DD, DD);
    scatter_av_kernel<<<(BB*NQ*64)/256, 256, 0, stream>>>(MAVP, X);

    // ---- transformer layers (bf16 MFMA) ----
    for (int l = 0; l < NLAYER; ++l) {
        ln_kernel<1><<<BT/4, 256, 0, stream>>>(X, ln1_s + l*DD, ln1_b + l*DD, Hb, BT);
        gemm_bf16<0,0,1><<<dim3(208, 6), 256, 0, stream>>>(
            Hb, 256, Wqkv + (size_t)l*768*256, bqkv + l*768,
            (const float*)nullptr, QKVb, 768, 256);
        transpose_v<<<dim3(13, NH, BB), 256, 0, stream>>>(QKVb, Vt);
        attn_mfma<<<dim3(13, NH, BB), 256, 0, stream>>>(QKVb, Vt, Ob);
        gemm_bf16<0,1,0><<<dim3(208, 2), 256, 0, stream>>>(
            Ob, 256, Wo + (size_t)l*256*256, bo + l*DD, X, X, 256, 256);
        ln_kernel<1><<<BT/4, 256, 0, stream>>>(X, ln2_s + l*DD, ln2_b + l*DD, Hb, BT);
        gemm_bf16<1,0,1><<<dim3(208, 8), 256, 0, stream>>>(
            Hb, 256, W1t + (size_t)l*1024*256, b1 + l*FF,
            (const float*)nullptr, MID, 1024, 256);
        gemm_bf16<0,1,0><<<dim3(208, 2), 256, 0, stream>>>(
            MID, 1024, W2t + (size_t)l*256*1024, b2 + l*DD, X, X, 256, 1024);
    }

    // ---- post-stage (fp32) ----
    gather_h_kernel<<<(BB*NHID*64)/256, 256, 0, stream>>>(X, HX);
    ln_kernel<0><<<(BB*NHID)/4, 256, 0, stream>>>(HX, lnf_s, lnf_b, HXN, BB*NHID);
    GEMMF(2, false, HXN, ha_w1, ha_b1, (const float*)nullptr, A1, BB*NHID, DD, DD);
    GEMMF(2, false, A1,  ha_w2, ha_b2, (const float*)nullptr, A2, BB*NHID, DD, DD);
    GEMMF(2, false, HXN, hv_w1, hv_b1, (const float*)nullptr, V1, BB*NHID, DD, DD);
    GEMMF(2, false, V1,  hv_w2, hv_b2, (const float*)nullptr, V2, BB*NHID, DD, DD);
    head_final<<<BB*NHID, 64, 0, stream>>>(A2, ha_w3, ha_b3, V2, hv_w3, hv_b3, (float*)d_out);
    #undef GEMMF
}